// Round 2
// baseline (466.222 us; speedup 1.0000x reference)
//
#include <hip/hip_runtime.h>

typedef __bf16 bf16x8 __attribute__((ext_vector_type(8)));
typedef float f32x4 __attribute__((ext_vector_type(4)));
typedef unsigned short u16;

#define EMB 1024
#define SEQ 2048
#define BATCH 2
#define HEADS 16
#define HEAD_DIM 64
#define FF 4096
#define ROWS (BATCH * SEQ)  // 4096

static __device__ __forceinline__ u16 f2bf(float f) {
    unsigned int u = __builtin_bit_cast(unsigned int, f);
    unsigned int r = (u + 0x7FFFu + ((u >> 16) & 1u)) >> 16;
    return (u16)r;
}

// ---------------- transpose + convert: f32 [R][C] -> bf16 [C][R] ----------------
__global__ __launch_bounds__(256) void transpose_f32_to_bf16(
    const float* __restrict__ in, u16* __restrict__ out, int R, int C) {
    __shared__ float tile[32][33];
    int c0 = blockIdx.x * 32, r0 = blockIdx.y * 32;
    int tx = threadIdx.x & 31, ty = threadIdx.x >> 5;  // ty: 0..7
#pragma unroll
    for (int i = 0; i < 32; i += 8)
        tile[ty + i][tx] = in[(size_t)(r0 + ty + i) * C + c0 + tx];
    __syncthreads();
#pragma unroll
    for (int i = 0; i < 32; i += 8)
        out[(size_t)(c0 + ty + i) * R + r0 + tx] = f2bf(tile[tx][ty + i]);
}

// ---------------- LayerNorm: f32 [rows][1024] -> bf16 ----------------
__global__ __launch_bounds__(256) void ln_kernel(
    const float* __restrict__ x, const float* __restrict__ gamma,
    const float* __restrict__ beta, u16* __restrict__ out) {
    int row = blockIdx.x;
    int t = threadIdx.x;
    float4 v = reinterpret_cast<const float4*>(x + (size_t)row * EMB)[t];
    float s = v.x + v.y + v.z + v.w;
    float s2 = v.x * v.x + v.y * v.y + v.z * v.z + v.w * v.w;
#pragma unroll
    for (int off = 1; off < 64; off <<= 1) {
        s += __shfl_xor(s, off);
        s2 += __shfl_xor(s2, off);
    }
    __shared__ float sm[8];
    int wid = t >> 6;
    if ((t & 63) == 0) { sm[wid] = s; sm[wid + 4] = s2; }
    __syncthreads();
    s = sm[0] + sm[1] + sm[2] + sm[3];
    s2 = sm[4] + sm[5] + sm[6] + sm[7];
    float mean = s * (1.0f / EMB);
    float var = s2 * (1.0f / EMB) - mean * mean;
    float inv = rsqrtf(var + 1e-5f);
    float4 gv = reinterpret_cast<const float4*>(gamma)[t];
    float4 bv = reinterpret_cast<const float4*>(beta)[t];
    ushort4 o;
    o.x = f2bf((v.x - mean) * inv * gv.x + bv.x);
    o.y = f2bf((v.y - mean) * inv * gv.y + bv.y);
    o.z = f2bf((v.z - mean) * inv * gv.z + bv.z);
    o.w = f2bf((v.w - mean) * inv * gv.w + bv.w);
    reinterpret_cast<ushort4*>(out + (size_t)row * EMB)[t] = o;
}

// ---------------- GEMM: C[M][N] = A[M][K] (bf16) x Bt[N][K] (bf16) ----------------
// EPI 0: bf16 out.  EPI 1: f32 out = acc + bias[n] + resid[m*N+n].
// EPI 2: bf16 out = gelu(acc + bias[n]).  EPI 3: bf16 Vt write out[(b*1024+n)*2048+s].
template <int EPI>
__global__ __launch_bounds__(256) void gemm_bf16(
    const u16* __restrict__ A, const u16* __restrict__ B, void* __restrict__ Cout,
    const float* __restrict__ bias, const float* __restrict__ resid,
    int M, int N, int K) {
    __shared__ u16 As[128 * 72];
    __shared__ u16 Bs[128 * 72];
    int tm = blockIdx.x * 128;
    int tn = blockIdx.y * 128;
    int t = threadIdx.x;
    int lane = t & 63, wid = t >> 6;
    int wr = (wid >> 1) * 64, wc = (wid & 1) * 64;
    int l15 = lane & 15, g = lane >> 4;
    f32x4 acc[4][4] = {};
    for (int k0 = 0; k0 < K; k0 += 64) {
        __syncthreads();
#pragma unroll
        for (int p = 0; p < 4; ++p) {
            int chunk = t + p * 256;
            int row = chunk >> 3, c16 = chunk & 7;
            uint4 av = *reinterpret_cast<const uint4*>(A + (size_t)(tm + row) * K + k0 + c16 * 8);
            *reinterpret_cast<uint4*>(&As[row * 72 + c16 * 8]) = av;
            uint4 bv = *reinterpret_cast<const uint4*>(B + (size_t)(tn + row) * K + k0 + c16 * 8);
            *reinterpret_cast<uint4*>(&Bs[row * 72 + c16 * 8]) = bv;
        }
        __syncthreads();
#pragma unroll
        for (int kc = 0; kc < 2; ++kc) {
            int ko = kc * 32 + g * 8;
            bf16x8 af[4], bfr[4];
#pragma unroll
            for (int i = 0; i < 4; ++i)
                af[i] = *reinterpret_cast<const bf16x8*>(&As[(wr + i * 16 + l15) * 72 + ko]);
#pragma unroll
            for (int j = 0; j < 4; ++j)
                bfr[j] = *reinterpret_cast<const bf16x8*>(&Bs[(wc + j * 16 + l15) * 72 + ko]);
#pragma unroll
            for (int i = 0; i < 4; ++i)
#pragma unroll
                for (int j = 0; j < 4; ++j)
                    acc[i][j] = __builtin_amdgcn_mfma_f32_16x16x32_bf16(af[i], bfr[j], acc[i][j], 0, 0, 0);
        }
    }
    int mb = tm + wr + g * 4;
    int nb = tn + wc + l15;
#pragma unroll
    for (int i = 0; i < 4; ++i) {
#pragma unroll
        for (int j = 0; j < 4; ++j) {
            int n = nb + j * 16;
#pragma unroll
            for (int r = 0; r < 4; ++r) {
                int m = mb + i * 16 + r;
                float val = acc[i][j][r];
                if constexpr (EPI == 0) {
                    ((u16*)Cout)[(size_t)m * N + n] = f2bf(val);
                } else if constexpr (EPI == 1) {
                    ((float*)Cout)[(size_t)m * N + n] =
                        val + bias[n] + resid[(size_t)m * N + n];
                } else if constexpr (EPI == 2) {
                    float xg = val + bias[n];
                    float x3 = xg + 0.044715f * xg * xg * xg;
                    float tz = 0.7978845608028654f * x3;
                    float th = 1.0f - 2.0f / (1.0f + __expf(2.0f * tz));
                    ((u16*)Cout)[(size_t)m * N + n] = f2bf(0.5f * xg * (1.0f + th));
                } else {  // EPI 3: V transposed write
                    int bb = m >> 11, ss = m & 2047;
                    ((u16*)Cout)[((size_t)(bb * EMB + n)) * SEQ + ss] = f2bf(val);
                }
            }
        }
    }
}

// ---------------- Flash attention (causal), bf16 MFMA ----------------
// Qb, Kb: [4096][1024] bf16 (row = b*2048+s, col = h*64+d)
// Vt: [2][1024][2048] bf16 (Vt[b][h*64+d][s])
// ctx: [4096][1024] bf16
__global__ __launch_bounds__(256) void attn_kernel(
    const u16* __restrict__ Qb, const u16* __restrict__ Kb,
    const u16* __restrict__ Vt, u16* __restrict__ ctx) {
    __shared__ u16 P_lds[4][32][72];
    int bh = blockIdx.x;
    int b = bh >> 4, h = bh & 15;
    int qtile = blockIdx.y;
    int lane = threadIdx.x & 63, wid = threadIdx.x >> 6;
    int l15 = lane & 15, g = lane >> 4;
    int qbase = qtile * 128 + wid * 32;

    bf16x8 qf[2][2];
#pragma unroll
    for (int qt = 0; qt < 2; ++qt)
#pragma unroll
        for (int kc = 0; kc < 2; ++kc)
            qf[qt][kc] = *reinterpret_cast<const bf16x8*>(
                Qb + (size_t)(b * SEQ + qbase + qt * 16 + l15) * EMB + h * 64 + kc * 32 + g * 8);

    f32x4 ctx_acc[2][4] = {};
    float mrun[2] = {-1e30f, -1e30f};
    float lrun[2] = {0.f, 0.f};
    int nkt = qbase / 64 + 1;

    for (int kt = 0; kt < nkt; ++kt) {
        int k0 = kt * 64;
        // S^T = K . Q^T  (sacc[ktile][qt]: row=key=g*4+r, col=q=l15)
        f32x4 sacc[4][2] = {};
#pragma unroll
        for (int kc = 0; kc < 2; ++kc) {
#pragma unroll
            for (int ktile = 0; ktile < 4; ++ktile) {
                bf16x8 kf = *reinterpret_cast<const bf16x8*>(
                    Kb + (size_t)(b * SEQ + k0 + ktile * 16 + l15) * EMB + h * 64 + kc * 32 + g * 8);
#pragma unroll
                for (int qt = 0; qt < 2; ++qt)
                    sacc[ktile][qt] = __builtin_amdgcn_mfma_f32_16x16x32_bf16(
                        kf, qf[qt][kc], sacc[ktile][qt], 0, 0, 0);
            }
        }
#pragma unroll
        for (int qt = 0; qt < 2; ++qt) {
            int q = qbase + qt * 16 + l15;
            float sv[16];
            float tmax = -1e30f;
#pragma unroll
            for (int ktile = 0; ktile < 4; ++ktile)
#pragma unroll
                for (int r = 0; r < 4; ++r) {
                    int key = k0 + ktile * 16 + g * 4 + r;
                    float sx = sacc[ktile][qt][r] * 0.125f;
                    if (key > q) sx = -1e30f;
                    sv[ktile * 4 + r] = sx;
                    tmax = fmaxf(tmax, sx);
                }
            tmax = fmaxf(tmax, __shfl_xor(tmax, 16));
            tmax = fmaxf(tmax, __shfl_xor(tmax, 32));
            float mnew = fmaxf(mrun[qt], tmax);
            float corr = __expf(mrun[qt] - mnew);
            mrun[qt] = mnew;
            float psum = 0.f;
#pragma unroll
            for (int idx = 0; idx < 16; ++idx) {
                float p = __expf(sv[idx] - mnew);
                sv[idx] = p;
                psum += p;
            }
            lrun[qt] = lrun[qt] * corr + psum;
            float corr4[4];
#pragma unroll
            for (int r = 0; r < 4; ++r) corr4[r] = __shfl(corr, g * 4 + r);
#pragma unroll
            for (int dt = 0; dt < 4; ++dt)
#pragma unroll
                for (int r = 0; r < 4; ++r) ctx_acc[qt][dt][r] *= corr4[r];
#pragma unroll
            for (int ktile = 0; ktile < 4; ++ktile)
#pragma unroll
                for (int r = 0; r < 4; ++r)
                    P_lds[wid][qt * 16 + l15][ktile * 16 + g * 4 + r] = f2bf(sv[ktile * 4 + r]);
        }
        asm volatile("s_waitcnt lgkmcnt(0)" ::: "memory");
        // ctx += P . V
#pragma unroll
        for (int kc = 0; kc < 2; ++kc) {
            bf16x8 pf[2];
#pragma unroll
            for (int qt = 0; qt < 2; ++qt)
                pf[qt] = *reinterpret_cast<const bf16x8*>(&P_lds[wid][qt * 16 + l15][kc * 32 + g * 8]);
#pragma unroll
            for (int dt = 0; dt < 4; ++dt) {
                bf16x8 vf = *reinterpret_cast<const bf16x8*>(
                    Vt + (size_t)(b * EMB + h * 64 + dt * 16 + l15) * SEQ + k0 + kc * 32 + g * 8);
#pragma unroll
                for (int qt = 0; qt < 2; ++qt)
                    ctx_acc[qt][dt] = __builtin_amdgcn_mfma_f32_16x16x32_bf16(
                        pf[qt], vf, ctx_acc[qt][dt], 0, 0, 0);
            }
        }
    }
#pragma unroll
    for (int qt = 0; qt < 2; ++qt) {
        float lsum = lrun[qt];
        lsum += __shfl_xor(lsum, 16);
        lsum += __shfl_xor(lsum, 32);
        float d4[4];
#pragma unroll
        for (int r = 0; r < 4; ++r) d4[r] = __shfl(lsum, g * 4 + r);
#pragma unroll
        for (int dt = 0; dt < 4; ++dt)
#pragma unroll
            for (int r = 0; r < 4; ++r) {
                int q = qbase + qt * 16 + g * 4 + r;
                int d = h * 64 + dt * 16 + l15;
                ctx[(size_t)(b * SEQ + q) * EMB + d] = f2bf(ctx_acc[qt][dt][r] / d4[r]);
            }
    }
}

extern "C" void kernel_launch(void* const* d_in, const int* in_sizes, int n_in,
                              void* d_out, int out_size, void* d_ws, size_t ws_size,
                              hipStream_t stream) {
    const float* x    = (const float*)d_in[0];
    const float* Wq   = (const float*)d_in[1];
    const float* Wk   = (const float*)d_in[2];
    const float* Wv   = (const float*)d_in[3];
    const float* Wo   = (const float*)d_in[4];
    const float* bo   = (const float*)d_in[5];
    const float* ln1g = (const float*)d_in[6];
    const float* ln1b = (const float*)d_in[7];
    const float* ln2g = (const float*)d_in[8];
    const float* ln2b = (const float*)d_in[9];
    const float* W1   = (const float*)d_in[10];
    const float* b1   = (const float*)d_in[11];
    const float* W2   = (const float*)d_in[12];
    const float* b2   = (const float*)d_in[13];

    char* ws = (char*)d_ws;
    size_t off = 0;
    auto alloc = [&](size_t bytes) {
        void* p = ws + off;
        off += (bytes + 255) & ~(size_t)255;
        return p;
    };
    u16* h1   = (u16*)alloc((size_t)ROWS * EMB * 2);
    u16* Wqt  = (u16*)alloc((size_t)EMB * EMB * 2);
    u16* Wkt  = (u16*)alloc((size_t)EMB * EMB * 2);
    u16* Wvt  = (u16*)alloc((size_t)EMB * EMB * 2);
    u16* Wot  = (u16*)alloc((size_t)EMB * EMB * 2);
    u16* W1t  = (u16*)alloc((size_t)FF * EMB * 2);   // [4096][1024]
    u16* W2t  = (u16*)alloc((size_t)EMB * FF * 2);   // [1024][4096]
    u16* Qb   = (u16*)alloc((size_t)ROWS * EMB * 2);
    u16* Kb   = (u16*)alloc((size_t)ROWS * EMB * 2);
    u16* Vtb  = (u16*)alloc((size_t)BATCH * EMB * SEQ * 2);
    u16* ctxb = (u16*)alloc((size_t)ROWS * EMB * 2);
    float* x2 = (float*)alloc((size_t)ROWS * EMB * 4);
    u16* h2   = (u16*)alloc((size_t)ROWS * EMB * 2);
    u16* ff1  = (u16*)alloc((size_t)ROWS * FF * 2);

    // weight transposes (f32 [R][C] -> bf16 [C][R]); grid (C/32, R/32)
    transpose_f32_to_bf16<<<dim3(32, 32), 256, 0, stream>>>(Wq, Wqt, EMB, EMB);
    transpose_f32_to_bf16<<<dim3(32, 32), 256, 0, stream>>>(Wk, Wkt, EMB, EMB);
    transpose_f32_to_bf16<<<dim3(32, 32), 256, 0, stream>>>(Wv, Wvt, EMB, EMB);
    transpose_f32_to_bf16<<<dim3(32, 32), 256, 0, stream>>>(Wo, Wot, EMB, EMB);
    transpose_f32_to_bf16<<<dim3(128, 32), 256, 0, stream>>>(W1, W1t, EMB, FF);
    transpose_f32_to_bf16<<<dim3(32, 128), 256, 0, stream>>>(W2, W2t, FF, EMB);

    ln_kernel<<<ROWS, 256, 0, stream>>>(x, ln1g, ln1b, h1);

    gemm_bf16<0><<<dim3(32, 8), 256, 0, stream>>>(h1, Wqt, Qb, nullptr, nullptr, ROWS, EMB, EMB);
    gemm_bf16<0><<<dim3(32, 8), 256, 0, stream>>>(h1, Wkt, Kb, nullptr, nullptr, ROWS, EMB, EMB);
    gemm_bf16<3><<<dim3(32, 8), 256, 0, stream>>>(h1, Wvt, Vtb, nullptr, nullptr, ROWS, EMB, EMB);

    attn_kernel<<<dim3(32, 16), 256, 0, stream>>>(Qb, Kb, Vtb, ctxb);

    gemm_bf16<1><<<dim3(32, 8), 256, 0, stream>>>(ctxb, Wot, x2, bo, x, ROWS, EMB, EMB);

    ln_kernel<<<ROWS, 256, 0, stream>>>(x2, ln2g, ln2b, h2);

    gemm_bf16<2><<<dim3(32, 32), 256, 0, stream>>>(h2, W1t, ff1, b1, nullptr, ROWS, FF, EMB);
    gemm_bf16<1><<<dim3(32, 8), 256, 0, stream>>>(ff1, W2t, (float*)d_out, b2, x2, ROWS, EMB, FF);
}